// Round 10
// baseline (1254.108 us; speedup 1.0000x reference)
//
#include <hip/hip_runtime.h>
#include <hip/hip_bf16.h>
#include <cstdint>

// Problem constants (match setup_inputs)
constexpr int B  = 2;
constexpr int L  = 2048;
constexpr int S  = 2048;
constexpr int DM = 1024;
constexpr int H  = 16;
constexpr int R  = 32;     // rank
constexpr int DH = 64;     // head dim
constexpr int TOPK = 32;
constexpr int SELCAP = 36; // per-row selection capacity (>32 only on exact fp ties)
constexpr float SCALE = 0.17677669529663687f; // 1/sqrt(32)

// MEASURED (R4-R9): VGPR budget is set from LDS-implied occupancy
// (64KB LDS -> 2 blocks/CU -> 128-VGPR cap). LICM hoists loop-invariant LDS
// reads into registers -> spill; defeated with an opaque-zero asm index
// (R9: VGPR 64, no spill, 387 us). This round: 2 keys/lane (halves Q
// ds_reads) + double-buffered GEMM (34KB LDS -> 4-block target -> 128 cap).

// ---------------------------------------------------------------------------
// Tiled fp32 GEMM v2: double-buffered LDS, one barrier per K-step.
// C[M,N] = (A[M,K] @ W[K,N] + bias[N]) * outScale
// Per-output accumulation order identical to v1 (kb asc, kk asc, serial fmaf)
// -> bit-identical results.
// ---------------------------------------------------------------------------
__global__ __launch_bounds__(256, 2)
void gemm128_f32(const float* __restrict__ A, const float* __restrict__ W,
                 const float* __restrict__ bias, float* __restrict__ C,
                 int M, int N, int K, float outScale)
{
    __shared__ float As[2][16][136];
    __shared__ float Ws[2][16][132];

    const int t  = threadIdx.x;
    const int tx = t & 15;
    const int ty = t >> 4;
    const int m0 = blockIdx.y * 128;
    const int n0 = blockIdx.x * 128;

    // staging indices (constant per thread)
    const int a_row0 = t >> 2;            // f4 = t
    const int a_cg0  = (t & 3) * 4;
    const int a_row1 = (t + 256) >> 2;    // f4 = t + 256
    const int a_cg1  = ((t + 256) & 3) * 4;
    const int w_kk0  = t >> 5;
    const int w_cb0  = (t & 31) * 4;
    const int w_kk1  = (t + 256) >> 5;
    const int w_cb1  = ((t + 256) & 31) * 4;

    float acc[8][8];
#pragma unroll
    for (int i = 0; i < 8; ++i)
#pragma unroll
        for (int j = 0; j < 8; ++j) acc[i][j] = 0.f;

    float4 av0, av1, wv0, wv1;

    auto gload = [&](int kb) {
        av0 = *(const float4*)&A[(size_t)(m0 + a_row0) * K + kb + a_cg0];
        av1 = *(const float4*)&A[(size_t)(m0 + a_row1) * K + kb + a_cg1];
        wv0 = *(const float4*)&W[(size_t)(kb + w_kk0) * N + n0 + w_cb0];
        wv1 = *(const float4*)&W[(size_t)(kb + w_kk1) * N + n0 + w_cb1];
    };
    auto swrite = [&](int p) {
        As[p][a_cg0 + 0][a_row0] = av0.x;
        As[p][a_cg0 + 1][a_row0] = av0.y;
        As[p][a_cg0 + 2][a_row0] = av0.z;
        As[p][a_cg0 + 3][a_row0] = av0.w;
        As[p][a_cg1 + 0][a_row1] = av1.x;
        As[p][a_cg1 + 1][a_row1] = av1.y;
        As[p][a_cg1 + 2][a_row1] = av1.z;
        As[p][a_cg1 + 3][a_row1] = av1.w;
        *(float4*)&Ws[p][w_kk0][w_cb0] = wv0;
        *(float4*)&Ws[p][w_kk1][w_cb1] = wv1;
    };
    auto compute = [&](int p) {
#pragma unroll
        for (int kk = 0; kk < 16; ++kk) {
            float4 a0 = *(const float4*)&As[p][kk][ty * 8];
            float4 a1 = *(const float4*)&As[p][kk][ty * 8 + 4];
            float4 w0 = *(const float4*)&Ws[p][kk][tx * 8];
            float4 w1 = *(const float4*)&Ws[p][kk][tx * 8 + 4];
            float a[8] = {a0.x, a0.y, a0.z, a0.w, a1.x, a1.y, a1.z, a1.w};
            float w[8] = {w0.x, w0.y, w0.z, w0.w, w1.x, w1.y, w1.z, w1.w};
#pragma unroll
            for (int i = 0; i < 8; ++i)
#pragma unroll
                for (int j = 0; j < 8; ++j)
                    acc[i][j] = fmaf(a[i], w[j], acc[i][j]);
        }
    };

    // prologue: stage tile 0
    gload(0);
    swrite(0);
    __syncthreads();

    int p = 0;
#pragma unroll 1
    for (int kb = 16; kb < K; kb += 16) {
        gload(kb);          // issue next-tile loads (latency hidden by compute)
        compute(p);         // compute current buffer
        swrite(p ^ 1);      // write next tile into the other buffer
        __syncthreads();
        p ^= 1;
    }
    compute(p);             // final tile

    float4 b0 = *(const float4*)&bias[n0 + tx * 8];
    float4 b1 = *(const float4*)&bias[n0 + tx * 8 + 4];
#pragma unroll
    for (int i = 0; i < 8; ++i) {
        float4 o0 = make_float4((acc[i][0] + b0.x) * outScale, (acc[i][1] + b0.y) * outScale,
                                (acc[i][2] + b0.z) * outScale, (acc[i][3] + b0.w) * outScale);
        float4 o1 = make_float4((acc[i][4] + b1.x) * outScale, (acc[i][5] + b1.y) * outScale,
                                (acc[i][6] + b1.z) * outScale, (acc[i][7] + b1.w) * outScale);
        size_t off = (size_t)(m0 + ty * 8 + i) * N + n0 + tx * 8;
        *(float4*)&C[off]     = o0;
        *(float4*)&C[off + 4] = o1;
    }
}

// ---------------------------------------------------------------------------
// Kernel 1 (v9): 2 KEYS PER LANE (ka[2][8] = 64 VGPR), 2 chunks of 1024 keys.
// Halves the Q ds_read count (was 1:4 read:FMA, now 1:8) and doubles FMA ILP
// (independent s0/s1 chains). Anti-LICM opaque zero keeps Q reads inside the
// chunk loop (R9-proven). Per-(row,key) FMA order identical -> bit-identical.
// ---------------------------------------------------------------------------
__global__ __launch_bounds__(512, 1)
void score_select(const float* __restrict__ Qp, const float* __restrict__ Kp,
                  unsigned short* __restrict__ selIdx, float* __restrict__ selWt,
                  int* __restrict__ selCnt, float* __restrict__ selInv)
{
    __shared__ float  sclds[8][2048];   // 64 KB
    __shared__ float4 Qlds4[8][8];      // 1 KB (pre-scaled Q)

    const int t    = threadIdx.x;
    const int lane = t & 63;
    const int wv   = t >> 6;            // 0..7

    // XCD-aware swizzle: all 256 tiles of one (b,h) land on one XCD
    const int wgid = blockIdx.x;
    const int xcd  = wgid & 7;
    const int jj   = wgid >> 3;              // 0..1023
    const int bh   = xcd + 8 * (jj >> 8);    // 0..31
    const int tile = jj & 255;
    const int b    = bh >> 4;
    const int h    = bh & 15;
    const int lbase = tile * 8;

    const float* kbase = Kp + (size_t)b * S * (H * R) + h * R;
    const float* qbase = Qp + (size_t)(b * L + lbase) * (H * R) + h * R;

    // stage Q tile (8 rows x 8 quads)
    if (t < 64) {
        int row = t >> 3, q = t & 7;
        Qlds4[row][q] = *(const float4*)(qbase + (size_t)row * (H * R) + q * 4);
    }
    __syncthreads();   // Qlds4 ready

    // ---- score phase: 2 chunks of 1024 keys; 2 keys/lane in VGPRs ----
#pragma unroll 1
    for (int c = 0; c < 2; ++c) {
        float4 ka[2][8];
        const float* kp0 = kbase + (size_t)(c * 1024 + wv * 64 + lane) * (H * R);
        const float* kp1 = kbase + (size_t)(c * 1024 + 512 + wv * 64 + lane) * (H * R);
#pragma unroll
        for (int q = 0; q < 8; ++q) {
            ka[0][q] = *(const float4*)(kp0 + q * 4);
            ka[1][q] = *(const float4*)(kp1 + q * 4);
        }

        // ANTI-LICM: opaque zero, redefined every chunk (R9-proven).
        int zero;
        asm volatile("v_mov_b32 %0, 0" : "=v"(zero));

        const int k0 = c * 1024 + wv * 64 + lane;
#pragma unroll
        for (int r = 0; r < 8; ++r) {
            const float4* qrow = Qlds4[r + zero];
            float s0 = 0.f, s1 = 0.f;
#pragma unroll
            for (int q = 0; q < 8; ++q) {
                float4 qv = qrow[q];                // wave-uniform broadcast
                s0 = fmaf(qv.x, ka[0][q].x, s0);
                s0 = fmaf(qv.y, ka[0][q].y, s0);
                s0 = fmaf(qv.z, ka[0][q].z, s0);
                s0 = fmaf(qv.w, ka[0][q].w, s0);
                s1 = fmaf(qv.x, ka[1][q].x, s1);
                s1 = fmaf(qv.y, ka[1][q].y, s1);
                s1 = fmaf(qv.z, ka[1][q].z, s1);
                s1 = fmaf(qv.w, ka[1][q].w, s1);
            }
            sclds[r][k0]       = s0;
            sclds[r][k0 + 512] = s1;
        }
    }

    __syncthreads();

    // ---- selection: wave wv handles row wv (unchanged, bit-identical) ----
    const unsigned long long lanelt = (1ull << lane) - 1ull;
    {
        const int r     = wv;
        const int row_g = bh * L + lbase + r;

        float sreg[32];
#pragma unroll
        for (int j = 0; j < 32; ++j) sreg[j] = sclds[r][j * 64 + lane];

        // row max (float domain)
        float mx = sreg[0];
#pragma unroll
        for (int j = 1; j < 32; ++j) mx = fmaxf(mx, sreg[j]);
#pragma unroll
        for (int off = 32; off >= 1; off >>= 1)
            mx = fmaxf(mx, __shfl_xor(mx, off, 64));

        // in-place sortable-uint conversion (monotone bijection)
#pragma unroll
        for (int j = 0; j < 32; ++j) {
            unsigned int bb  = __float_as_uint(sreg[j]);
            unsigned int sgn = (unsigned int)(((int)bb) >> 31);
            sreg[j] = __uint_as_float(bb ^ (sgn | 0x80000000u));
        }

        // MSB radix select with exact-count early exit
        unsigned int P = 0;
        for (int bit = 31; bit >= 0; --bit) {
            unsigned int test = P | (1u << bit);
            int c2 = 0;
#pragma unroll
            for (int j = 0; j < 32; ++j)
                c2 += (int)__popcll(__ballot(__float_as_uint(sreg[j]) >= test));
            if (c2 >= TOPK) {
                P = test;
                if (c2 == TOPK) break;
            }
        }

        // single exp pass: emit (idx, unnormalized weight) + denominator
        float dsum = 0.f;
        int   base = 0;
#pragma unroll
        for (int j = 0; j < 32; ++j) {
            unsigned int u = __float_as_uint(sreg[j]);
            bool sel = (u >= P);
            unsigned int sg2  = (unsigned int)(((int)u) >> 31);
            unsigned int mask = 0x80000000u | ~sg2;
            float forig = __uint_as_float(u ^ mask);
            float e = __expf(forig - mx);
            unsigned long long m = __ballot(sel);
            if (sel) {
                int pos = base + (int)__popcll(m & lanelt);
                if (pos < SELCAP) {
                    selIdx[(size_t)row_g * SELCAP + pos] = (unsigned short)(j * 64 + lane);
                    selWt[(size_t)row_g * SELCAP + pos] = e;
                }
            }
            dsum += sel ? e : 0.f;
            base += (int)__popcll(m);
        }
#pragma unroll
        for (int off = 32; off >= 1; off >>= 1)
            dsum += __shfl_xor(dsum, off, 64);
        if (lane == 0) {
            selInv[row_g] = 1.0f / dsum;
            selCnt[row_g] = base < SELCAP ? base : SELCAP;
        }
    }
}

// ---------------------------------------------------------------------------
// Kernel 2: sparse PV gather (unchanged). One wave per row, lane = output dim.
// ---------------------------------------------------------------------------
__global__ __launch_bounds__(256)
void pv_gather(const float* __restrict__ Vp, const unsigned short* __restrict__ selIdx,
               const float* __restrict__ selWt, const int* __restrict__ selCnt,
               const float* __restrict__ selInv, float* __restrict__ Oh)
{
    const int t    = threadIdx.x;
    const int lane = t & 63;
    const int wv   = t >> 6;

    const int wg   = blockIdx.x;              // 0..16383
    const int xcd  = wg & 7;
    const int jj   = wg >> 3;                 // 0..2047
    const int bh   = xcd + 8 * (jj >> 9);     // 0..31
    const int tile = jj & 511;
    const int b    = bh >> 4;
    const int h    = bh & 15;
    const int l    = tile * 4 + wv;
    const int row_g = bh * L + l;

    int   cn  = selCnt[row_g];
    cn = cn < SELCAP ? cn : SELCAP;
    const float inv = selInv[row_g];
    const float* vb = Vp + (size_t)b * S * DM + h * DH + lane;
    const unsigned short* si = selIdx + (size_t)row_g * SELCAP;
    const float*          sw = selWt  + (size_t)row_g * SELCAP;

    float a0 = 0.f, a1 = 0.f, a2 = 0.f, a3 = 0.f;
    int tt = 0;
    for (; tt + 4 <= cn; tt += 4) {
        int   s0 = si[tt + 0], s1 = si[tt + 1], s2 = si[tt + 2], s3 = si[tt + 3];
        float w0 = sw[tt + 0], w1 = sw[tt + 1], w2 = sw[tt + 2], w3 = sw[tt + 3];
        a0 = fmaf(w0, vb[(size_t)s0 * DM], a0);
        a1 = fmaf(w1, vb[(size_t)s1 * DM], a1);
        a2 = fmaf(w2, vb[(size_t)s2 * DM], a2);
        a3 = fmaf(w3, vb[(size_t)s3 * DM], a3);
    }
    for (; tt < cn; ++tt) {
        int s0 = si[tt];
        a0 = fmaf(sw[tt], vb[(size_t)s0 * DM], a0);
    }
    Oh[(size_t)(b * L + l) * DM + h * DH + lane] = ((a0 + a1) + (a2 + a3)) * inv;
}

// ---------------------------------------------------------------------------
extern "C" void kernel_launch(void* const* d_in, const int* in_sizes, int n_in,
                              void* d_out, int out_size, void* d_ws, size_t ws_size,
                              hipStream_t stream)
{
    const float* q  = (const float*)d_in[0];
    const float* k  = (const float*)d_in[1];
    const float* v  = (const float*)d_in[2];
    const float* Wq = (const float*)d_in[3];
    const float* bq = (const float*)d_in[4];
    const float* Wk = (const float*)d_in[5];
    const float* bk = (const float*)d_in[6];
    const float* Wv = (const float*)d_in[7];
    const float* bv = (const float*)d_in[8];
    const float* Wo = (const float*)d_in[9];
    const float* bo = (const float*)d_in[10];
    // d_in[11] = pos_bias: per-head additive constant -> top-k/softmax invariant -> no-op.

    float* out = (float*)d_out;
    char*  ws  = (char*)d_ws;

    const size_t MB = 1024 * 1024;
    float* Qp = (float*)(ws);             //  8 MiB: (B*L, 512)  (pre-scaled by 1/sqrt(R))
    float* Kp = (float*)(ws + 8  * MB);   //  8 MiB: (B*S, 512)
    float* Vp = (float*)(ws + 16 * MB);   // 16 MiB: (B*S, 1024)
    float* Oh = (float*)(ws + 32 * MB);   // 16 MiB: (B*L, 1024)
    unsigned short* selIdx = (unsigned short*)(ws + 48 * MB);     // 4.72 MiB
    float*          selWt  = (float*)(ws + 53 * MB);              // 9.44 MiB
    int*            selCnt = (int*)(ws + 63 * MB);                // 0.25 MiB
    float*          selInv = (float*)(ws + 63 * MB + 512 * 1024); // 0.25 MiB

    const int M = B * L;  // 4096
    dim3 blk(256);

    gemm128_f32<<<dim3((H * R) / 128, M / 128), blk, 0, stream>>>(q, Wq, bq, Qp, M, H * R, DM, SCALE);
    gemm128_f32<<<dim3((H * R) / 128, M / 128), blk, 0, stream>>>(k, Wk, bk, Kp, M, H * R, DM, 1.0f);
    gemm128_f32<<<dim3(DM / 128, M / 128),      blk, 0, stream>>>(v, Wv, bv, Vp, M, DM, DM, 1.0f);

    score_select<<<dim3(8192), dim3(512), 0, stream>>>(Qp, Kp, selIdx, selWt, selCnt, selInv);
    pv_gather  <<<dim3(16384), blk, 0, stream>>>(Vp, selIdx, selWt, selCnt, selInv, Oh);

    gemm128_f32<<<dim3(DM / 128, M / 128),      blk, 0, stream>>>(Oh, Wo, bo, out, M, DM, DM, 1.0f);
}

// Round 11
// 761.782 us; speedup vs baseline: 1.6463x; 1.6463x over previous
//
#include <hip/hip_runtime.h>
#include <hip/hip_bf16.h>
#include <cstdint>

// Problem constants (match setup_inputs)
constexpr int B  = 2;
constexpr int L  = 2048;
constexpr int S  = 2048;
constexpr int DM = 1024;
constexpr int H  = 16;
constexpr int R  = 32;     // rank
constexpr int DH = 64;     // head dim
constexpr int TOPK = 32;
constexpr int SELCAP = 36;
constexpr float SCALE = 0.17677669529663687f; // 1/sqrt(32)

// MEASURED (R4-R10): VGPR cap = min(launch_bounds cap, LDS-occupancy cap)
// (64KB LDS -> 2 blocks/CU -> 128 cap; 56KB -> 2 blocks -> 256 w/ bounds(…,1)).
// LICM hoists loop-invariant LDS reads -> spill; defeat with opaque-zero asm.
// R10 lesson: 2-keys/lane + GEMM dbuf both regressed -> reverted to R9 forms.

using short8 = __attribute__((ext_vector_type(8))) short;
using f32x4  = __attribute__((ext_vector_type(4))) float;

__device__ __forceinline__ unsigned short bf16_rne(float x) {
    unsigned int u = __float_as_uint(x);
    unsigned int r = u + 0x7FFFu + ((u >> 16) & 1u);
    return (unsigned short)(r >> 16);
}

// ---------------------------------------------------------------------------
// Tiled fp32 GEMM v1 (R9-proven): C = (A@W + bias) * outScale.
// Used ONLY for Q/K projections (their bits feed top-k selection -> must stay
// bit-identical to prior rounds).
// ---------------------------------------------------------------------------
__global__ __launch_bounds__(256, 2)
void gemm128_f32(const float* __restrict__ A, const float* __restrict__ W,
                 const float* __restrict__ bias, float* __restrict__ C,
                 int M, int N, int K, float outScale)
{
    __shared__ float As[16][136];
    __shared__ float Ws[16][132];

    const int t  = threadIdx.x;
    const int tx = t & 15;
    const int ty = t >> 4;
    const int m0 = blockIdx.y * 128;
    const int n0 = blockIdx.x * 128;

    float acc[8][8];
#pragma unroll
    for (int i = 0; i < 8; ++i)
#pragma unroll
        for (int j = 0; j < 8; ++j) acc[i][j] = 0.f;

    for (int kb = 0; kb < K; kb += 16) {
        __syncthreads();
#pragma unroll
        for (int it = 0; it < 2; ++it) {
            int f4  = t + it * 256;
            int row = f4 >> 2;
            int cg  = (f4 & 3) * 4;
            float4 av = *(const float4*)&A[(size_t)(m0 + row) * K + kb + cg];
            As[cg + 0][row] = av.x;
            As[cg + 1][row] = av.y;
            As[cg + 2][row] = av.z;
            As[cg + 3][row] = av.w;
        }
#pragma unroll
        for (int it = 0; it < 2; ++it) {
            int f4 = t + it * 256;
            int kk = f4 >> 5;
            int cb = (f4 & 31) * 4;
            *(float4*)&Ws[kk][cb] = *(const float4*)&W[(size_t)(kb + kk) * N + n0 + cb];
        }
        __syncthreads();
#pragma unroll
        for (int kk = 0; kk < 16; ++kk) {
            float4 a0 = *(const float4*)&As[kk][ty * 8];
            float4 a1 = *(const float4*)&As[kk][ty * 8 + 4];
            float4 w0 = *(const float4*)&Ws[kk][tx * 8];
            float4 w1 = *(const float4*)&Ws[kk][tx * 8 + 4];
            float a[8] = {a0.x, a0.y, a0.z, a0.w, a1.x, a1.y, a1.z, a1.w};
            float w[8] = {w0.x, w0.y, w0.z, w0.w, w1.x, w1.y, w1.z, w1.w};
#pragma unroll
            for (int i = 0; i < 8; ++i)
#pragma unroll
                for (int j = 0; j < 8; ++j)
                    acc[i][j] = fmaf(a[i], w[j], acc[i][j]);
        }
    }

    float4 b0 = *(const float4*)&bias[n0 + tx * 8];
    float4 b1 = *(const float4*)&bias[n0 + tx * 8 + 4];
#pragma unroll
    for (int i = 0; i < 8; ++i) {
        float4 o0 = make_float4((acc[i][0] + b0.x) * outScale, (acc[i][1] + b0.y) * outScale,
                                (acc[i][2] + b0.z) * outScale, (acc[i][3] + b0.w) * outScale);
        float4 o1 = make_float4((acc[i][4] + b1.x) * outScale, (acc[i][5] + b1.y) * outScale,
                                (acc[i][6] + b1.z) * outScale, (acc[i][7] + b1.w) * outScale);
        size_t off = (size_t)(m0 + ty * 8 + i) * N + n0 + tx * 8;
        *(float4*)&C[off]     = o0;
        *(float4*)&C[off + 4] = o1;
    }
}

// ---------------------------------------------------------------------------
// Transpose + split fp32 W[K][N] -> bf16 hi/lo Th[N][K], Tl[N][K].
// Runs once per launch; ~1M elements, trivial bandwidth.
// ---------------------------------------------------------------------------
__global__ __launch_bounds__(256)
void transpose_split(const float* __restrict__ W, unsigned short* __restrict__ Th,
                     unsigned short* __restrict__ Tl, int N, int K)
{
    __shared__ float tile[32][33];
    const int n0 = blockIdx.x * 32;
    const int k0 = blockIdx.y * 32;
    const int tx = threadIdx.x & 31;
    const int ty = threadIdx.x >> 5;   // 0..7

#pragma unroll
    for (int i = ty; i < 32; i += 8)
        tile[i][tx] = W[(size_t)(k0 + i) * N + n0 + tx];
    __syncthreads();
#pragma unroll
    for (int i = ty; i < 32; i += 8) {
        float x = tile[tx][i];                     // = W[k0+tx][n0+i]
        unsigned short h = bf16_rne(x);
        float hf = __uint_as_float((unsigned int)h << 16);
        unsigned short l = bf16_rne(x - hf);
        Th[(size_t)(n0 + i) * K + k0 + tx] = h;
        Tl[(size_t)(n0 + i) * K + k0 + tx] = l;
    }
}

// ---------------------------------------------------------------------------
// Split-bf16 MFMA GEMM: C[M][N] = A[M][K](fp32) @ W + bias, where W is given
// as pre-transposed bf16 hi/lo Bh/Bl[N][K]. 3 MFMA passes per K-step:
// hi*hi + hi*lo + lo*hi (lo*lo dropped, ~2^-18 relative).
// 128x128 tile, BK=32, 4 waves; wave (wr,wc) owns a 64x64 sub-tile of 4x4
// 16x16x32 fragments. Both A and B frags loaded K-contiguous with the same
// lane map (k-permutation cancels in the dot product). C/D mapping per the
// HW-verified layout: col=lane&15, row=(lane>>4)*4+reg.
// LDS = 56KB -> 2 blocks/CU -> 256-VGPR cap (no spill; demand ~170).
// ---------------------------------------------------------------------------
__global__ __launch_bounds__(256, 1)
void gemm_mfma_split(const float* __restrict__ A, const unsigned short* __restrict__ Bh,
                     const unsigned short* __restrict__ Bl, const float* __restrict__ bias,
                     float* __restrict__ C, int M, int N, int K)
{
    constexpr int LDT = 56;   // LDS row stride in bf16 elems (112B: 28-bank stride, ~2-way max)
    __shared__ unsigned short Ah[128 * LDT];
    __shared__ unsigned short Al[128 * LDT];
    __shared__ unsigned short Wh[128 * LDT];
    __shared__ unsigned short Wl[128 * LDT];

    const int t    = threadIdx.x;
    const int lane = t & 63;
    const int w    = t >> 6;
    const int wr   = w >> 1;          // 0..1
    const int wc   = w & 1;           // 0..1
    const int l15  = lane & 15;
    const int l4   = lane >> 4;
    const int m0   = blockIdx.y * 128;
    const int n0   = blockIdx.x * 128;

    f32x4 acc[4][4];
#pragma unroll
    for (int m = 0; m < 4; ++m)
#pragma unroll
        for (int n = 0; n < 4; ++n) {
            f32x4 z = {0.f, 0.f, 0.f, 0.f};
            acc[m][n] = z;
        }

#pragma unroll 1
    for (int kb = 0; kb < K; kb += 32) {
        __syncthreads();   // previous step's frag reads done
        // stage A (fp32 -> hi/lo bf16) and B (bf16 copy), 128 rows x 32 k each
#pragma unroll
        for (int it = 0; it < 4; ++it) {
            int f   = t + it * 256;        // 0..1023
            int row = f >> 3;
            int kg  = (f & 7) * 4;
            float4 av = *(const float4*)&A[(size_t)(m0 + row) * K + kb + kg];
            ushort4 hv, lv;
            hv.x = bf16_rne(av.x); lv.x = bf16_rne(av.x - __uint_as_float((unsigned int)hv.x << 16));
            hv.y = bf16_rne(av.y); lv.y = bf16_rne(av.y - __uint_as_float((unsigned int)hv.y << 16));
            hv.z = bf16_rne(av.z); lv.z = bf16_rne(av.z - __uint_as_float((unsigned int)hv.z << 16));
            hv.w = bf16_rne(av.w); lv.w = bf16_rne(av.w - __uint_as_float((unsigned int)hv.w << 16));
            *(ushort4*)&Ah[row * LDT + kg] = hv;
            *(ushort4*)&Al[row * LDT + kg] = lv;
            ushort4 bh4 = *(const ushort4*)&Bh[(size_t)(n0 + row) * K + kb + kg];
            ushort4 bl4 = *(const ushort4*)&Bl[(size_t)(n0 + row) * K + kb + kg];
            *(ushort4*)&Wh[row * LDT + kg] = bh4;
            *(ushort4*)&Wl[row * LDT + kg] = bl4;
        }
        __syncthreads();

        short8 ah[4], al[4], bh[4], bl[4];
#pragma unroll
        for (int m = 0; m < 4; ++m) {
            int row = wr * 64 + m * 16 + l15;
            ah[m] = *(short8*)&Ah[row * LDT + l4 * 8];
            al[m] = *(short8*)&Al[row * LDT + l4 * 8];
        }
#pragma unroll
        for (int n = 0; n < 4; ++n) {
            int col = wc * 64 + n * 16 + l15;
            bh[n] = *(short8*)&Wh[col * LDT + l4 * 8];
            bl[n] = *(short8*)&Wl[col * LDT + l4 * 8];
        }
        // pass-major for ILP: 16 independent MFMAs between dependent pairs
#pragma unroll
        for (int m = 0; m < 4; ++m)
#pragma unroll
            for (int n = 0; n < 4; ++n)
                acc[m][n] = __builtin_amdgcn_mfma_f32_16x16x32_bf16(ah[m], bh[n], acc[m][n], 0, 0, 0);
#pragma unroll
        for (int m = 0; m < 4; ++m)
#pragma unroll
            for (int n = 0; n < 4; ++n)
                acc[m][n] = __builtin_amdgcn_mfma_f32_16x16x32_bf16(ah[m], bl[n], acc[m][n], 0, 0, 0);
#pragma unroll
        for (int m = 0; m < 4; ++m)
#pragma unroll
            for (int n = 0; n < 4; ++n)
                acc[m][n] = __builtin_amdgcn_mfma_f32_16x16x32_bf16(al[m], bh[n], acc[m][n], 0, 0, 0);
    }

    // epilogue: C/D layout col=lane&15, row=(lane>>4)*4+reg
#pragma unroll
    for (int m = 0; m < 4; ++m) {
        int row = m0 + wr * 64 + m * 16 + l4 * 4;
#pragma unroll
        for (int n = 0; n < 4; ++n) {
            int col = n0 + wc * 64 + n * 16 + l15;
            float bv = bias[col];
#pragma unroll
            for (int r = 0; r < 4; ++r)
                C[(size_t)(row + r) * N + col] = acc[m][n][r] + bv;
        }
    }
}

// ---------------------------------------------------------------------------
// Kernel 1 (exact R9 form, 387us proven): 8 rows/block, 64KB score LDS,
// K single-buffered ka[8], Q via LDS float4 broadcast + anti-LICM opaque zero.
// Bit-identical scores -> bit-identical selection.
// ---------------------------------------------------------------------------
__global__ __launch_bounds__(512, 1)
void score_select(const float* __restrict__ Qp, const float* __restrict__ Kp,
                  unsigned short* __restrict__ selIdx, float* __restrict__ selWt,
                  int* __restrict__ selCnt, float* __restrict__ selInv)
{
    __shared__ float  sclds[8][2048];   // 64 KB
    __shared__ float4 Qlds4[8][8];      // 1 KB (pre-scaled Q)

    const int t    = threadIdx.x;
    const int lane = t & 63;
    const int wv   = t >> 6;            // 0..7

    const int wgid = blockIdx.x;
    const int xcd  = wgid & 7;
    const int jj   = wgid >> 3;              // 0..1023
    const int bh   = xcd + 8 * (jj >> 8);    // 0..31
    const int tile = jj & 255;
    const int b    = bh >> 4;
    const int h    = bh & 15;
    const int lbase = tile * 8;

    const float* kbase = Kp + (size_t)b * S * (H * R) + h * R;
    const float* qbase = Qp + (size_t)(b * L + lbase) * (H * R) + h * R;

    if (t < 64) {
        int row = t >> 3, q = t & 7;
        Qlds4[row][q] = *(const float4*)(qbase + (size_t)row * (H * R) + q * 4);
    }
    __syncthreads();

#pragma unroll 1
    for (int c = 0; c < 4; ++c) {
        float4 ka[8];
        const float* kp = kbase + (size_t)(c * 512 + wv * 64 + lane) * (H * R);
#pragma unroll
        for (int q = 0; q < 8; ++q) ka[q] = *(const float4*)(kp + q * 4);

        int zero;
        asm volatile("v_mov_b32 %0, 0" : "=v"(zero));

        const int keyl = c * 512 + wv * 64 + lane;
#pragma unroll
        for (int r = 0; r < 8; ++r) {
            const float4* qrow = Qlds4[r + zero];
            float s = 0.f;
#pragma unroll
            for (int q = 0; q < 8; ++q) {
                float4 qv = qrow[q];
                s = fmaf(qv.x, ka[q].x, s);
                s = fmaf(qv.y, ka[q].y, s);
                s = fmaf(qv.z, ka[q].z, s);
                s = fmaf(qv.w, ka[q].w, s);
            }
            sclds[r][keyl] = s;
        }
    }

    __syncthreads();

    const unsigned long long lanelt = (1ull << lane) - 1ull;
    {
        const int r     = wv;
        const int row_g = bh * L + lbase + r;

        float sreg[32];
#pragma unroll
        for (int j = 0; j < 32; ++j) sreg[j] = sclds[r][j * 64 + lane];

        float mx = sreg[0];
#pragma unroll
        for (int j = 1; j < 32; ++j) mx = fmaxf(mx, sreg[j]);
#pragma unroll
        for (int off = 32; off >= 1; off >>= 1)
            mx = fmaxf(mx, __shfl_xor(mx, off, 64));

#pragma unroll
        for (int j = 0; j < 32; ++j) {
            unsigned int bb  = __float_as_uint(sreg[j]);
            unsigned int sgn = (unsigned int)(((int)bb) >> 31);
            sreg[j] = __uint_as_float(bb ^ (sgn | 0x80000000u));
        }

        unsigned int P = 0;
        for (int bit = 31; bit >= 0; --bit) {
            unsigned int test = P | (1u << bit);
            int c2 = 0;
#pragma unroll
            for (int j = 0; j < 32; ++j)
                c2 += (int)__popcll(__ballot(__float_as_uint(sreg[j]) >= test));
            if (c2 >= TOPK) {
                P = test;
                if (c2 == TOPK) break;
            }
        }

        float dsum = 0.f;
        int   base = 0;
#pragma unroll
        for (int j = 0; j < 32; ++j) {
            unsigned int u = __float_as_uint(sreg[j]);
            bool sel = (u >= P);
            unsigned int sg2  = (unsigned int)(((int)u) >> 31);
            unsigned int mask = 0x80000000u | ~sg2;
            float forig = __uint_as_float(u ^ mask);
            float e = __expf(forig - mx);
            unsigned long long m = __ballot(sel);
            if (sel) {
                int pos = base + (int)__popcll(m & lanelt);
                if (pos < SELCAP) {
                    selIdx[(size_t)row_g * SELCAP + pos] = (unsigned short)(j * 64 + lane);
                    selWt[(size_t)row_g * SELCAP + pos] = e;
                }
            }
            dsum += sel ? e : 0.f;
            base += (int)__popcll(m);
        }
#pragma unroll
        for (int off = 32; off >= 1; off >>= 1)
            dsum += __shfl_xor(dsum, off, 64);
        if (lane == 0) {
            selInv[row_g] = 1.0f / dsum;
            selCnt[row_g] = base < SELCAP ? base : SELCAP;
        }
    }
}

// ---------------------------------------------------------------------------
// Kernel 2: sparse PV gather (unchanged).
// ---------------------------------------------------------------------------
__global__ __launch_bounds__(256)
void pv_gather(const float* __restrict__ Vp, const unsigned short* __restrict__ selIdx,
               const float* __restrict__ selWt, const int* __restrict__ selCnt,
               const float* __restrict__ selInv, float* __restrict__ Oh)
{
    const int t    = threadIdx.x;
    const int lane = t & 63;
    const int wv   = t >> 6;

    const int wg   = blockIdx.x;              // 0..16383
    const int xcd  = wg & 7;
    const int jj   = wg >> 3;                 // 0..2047
    const int bh   = xcd + 8 * (jj >> 9);     // 0..31
    const int tile = jj & 511;
    const int b    = bh >> 4;
    const int h    = bh & 15;
    const int l    = tile * 4 + wv;
    const int row_g = bh * L + l;

    int   cn  = selCnt[row_g];
    cn = cn < SELCAP ? cn : SELCAP;
    const float inv = selInv[row_g];
    const float* vb = Vp + (size_t)b * S * DM + h * DH + lane;
    const unsigned short* si = selIdx + (size_t)row_g * SELCAP;
    const float*          sw = selWt  + (size_t)row_g * SELCAP;

    float a0 = 0.f, a1 = 0.f, a2 = 0.f, a3 = 0.f;
    int tt = 0;
    for (; tt + 4 <= cn; tt += 4) {
        int   s0 = si[tt + 0], s1 = si[tt + 1], s2 = si[tt + 2], s3 = si[tt + 3];
        float w0 = sw[tt + 0], w1 = sw[tt + 1], w2 = sw[tt + 2], w3 = sw[tt + 3];
        a0 = fmaf(w0, vb[(size_t)s0 * DM], a0);
        a1 = fmaf(w1, vb[(size_t)s1 * DM], a1);
        a2 = fmaf(w2, vb[(size_t)s2 * DM], a2);
        a3 = fmaf(w3, vb[(size_t)s3 * DM], a3);
    }
    for (; tt < cn; ++tt) {
        int s0 = si[tt];
        a0 = fmaf(sw[tt], vb[(size_t)s0 * DM], a0);
    }
    Oh[(size_t)(b * L + l) * DM + h * DH + lane] = ((a0 + a1) + (a2 + a3)) * inv;
}

// ---------------------------------------------------------------------------
extern "C" void kernel_launch(void* const* d_in, const int* in_sizes, int n_in,
                              void* d_out, int out_size, void* d_ws, size_t ws_size,
                              hipStream_t stream)
{
    const float* q  = (const float*)d_in[0];
    const float* k  = (const float*)d_in[1];
    const float* v  = (const float*)d_in[2];
    const float* Wq = (const float*)d_in[3];
    const float* bq = (const float*)d_in[4];
    const float* Wk = (const float*)d_in[5];
    const float* bk = (const float*)d_in[6];
    const float* Wv = (const float*)d_in[7];
    const float* bv = (const float*)d_in[8];
    const float* Wo = (const float*)d_in[9];
    const float* bo = (const float*)d_in[10];
    // d_in[11] = pos_bias: per-head additive constant -> top-k/softmax invariant -> no-op.

    float* out = (float*)d_out;
    char*  ws  = (char*)d_ws;

    const size_t MB = 1024 * 1024;
    float* Qp = (float*)(ws);             //  8 MiB: (B*L, 512) pre-scaled Q
    float* Kp = (float*)(ws + 8  * MB);   //  8 MiB: (B*S, 512)
    float* Vp = (float*)(ws + 16 * MB);   // 16 MiB: (B*S, 1024)
    float* Oh = (float*)(ws + 32 * MB);   // 16 MiB: (B*L, 1024)
    unsigned short* selIdx = (unsigned short*)(ws + 48 * MB);
    float*          selWt  = (float*)(ws + 53 * MB);
    int*            selCnt = (int*)(ws + 63 * MB);
    float*          selInv = (float*)(ws + 63 * MB + 512 * 1024);
    // Wt hi/lo reuse the Qp/Kp region AFTER score_select (2 MiB each)
    unsigned short* WtH = (unsigned short*)(ws);
    unsigned short* WtL = (unsigned short*)(ws + 4 * MB);

    const int M = B * L;  // 4096
    dim3 blk(256);

    // Q/K projections: fp32 v1 (bits feed top-k -> unchanged)
    gemm128_f32<<<dim3((H * R) / 128, M / 128), blk, 0, stream>>>(q, Wq, bq, Qp, M, H * R, DM, SCALE);
    gemm128_f32<<<dim3((H * R) / 128, M / 128), blk, 0, stream>>>(k, Wk, bk, Kp, M, H * R, DM, 1.0f);

    score_select<<<dim3(8192), dim3(512), 0, stream>>>(Qp, Kp, selIdx, selWt, selCnt, selInv);

    // V projection via split-bf16 MFMA (Qp region now dead)
    transpose_split<<<dim3(DM / 32, DM / 32), blk, 0, stream>>>(Wv, WtH, WtL, DM, DM);
    gemm_mfma_split<<<dim3(DM / 128, M / 128), blk, 0, stream>>>(v, WtH, WtL, bv, Vp, M, DM, DM);

    pv_gather<<<dim3(16384), blk, 0, stream>>>(Vp, selIdx, selWt, selCnt, selInv, Oh);

    // Output projection via split-bf16 MFMA
    transpose_split<<<dim3(DM / 32, DM / 32), blk, 0, stream>>>(Wo, WtH, WtL, DM, DM);
    gemm_mfma_split<<<dim3(DM / 128, M / 128), blk, 0, stream>>>(Oh, WtH, WtL, bo, out, M, DM, DM);
}

// Round 12
// 604.017 us; speedup vs baseline: 2.0763x; 1.2612x over previous
//
#include <hip/hip_runtime.h>
#include <hip/hip_bf16.h>
#include <cstdint>

// Problem constants (match setup_inputs)
constexpr int B  = 2;
constexpr int L  = 2048;
constexpr int S  = 2048;
constexpr int DM = 1024;
constexpr int H  = 16;
constexpr int R  = 32;     // rank
constexpr int DH = 64;     // head dim
constexpr int TOPK = 32;
constexpr int SELCAP = 36;
constexpr float SCALE = 0.17677669529663687f; // 1/sqrt(32)

// MEASURED (R4-R11): VGPR cap = LDS-implied occupancy cap (64KB -> 2 blk/CU
// -> 128 VGPR). LICM hoists loop-invariant LDS reads -> spill; defeated with
// opaque-zero asm index (R9: 64 VGPR, 387us). R10: 2-keys/lane + GEMM dbuf
// both regressed (reverted). R11: split-bf16 MFMA for Wv/Wo GEMMs OK
// (absmax unchanged). R12: merge QK proj (fill 256 CUs), fuse gather into
// score_select (kill 14MB sel* round-trip + 16k-block launch).

using short8 = __attribute__((ext_vector_type(8))) short;
using f32x4  = __attribute__((ext_vector_type(4))) float;

__device__ __forceinline__ unsigned short bf16_rne(float x) {
    unsigned int u = __float_as_uint(x);
    unsigned int r = u + 0x7FFFu + ((u >> 16) & 1u);
    return (unsigned short)(r >> 16);
}

// ---------------------------------------------------------------------------
// Merged Q/K projection: grid.z selects (q,Wq,bq,Qp,SCALE) vs (k,Wk,bk,Kp,1).
// Inner code identical to the R9-proven gemm128_f32 -> bit-identical outputs.
// 256 blocks total -> fills the chip (each alone was 128 blocks = half idle).
// ---------------------------------------------------------------------------
__global__ __launch_bounds__(256, 2)
void qk_proj(const float* __restrict__ Aq, const float* __restrict__ Wq_,
             const float* __restrict__ bq_, float* __restrict__ Cq,
             const float* __restrict__ Ak, const float* __restrict__ Wk_,
             const float* __restrict__ bk_, float* __restrict__ Ck,
             int M, int N, int K)
{
    const int z = blockIdx.z;
    const float* A    = z ? Ak  : Aq;
    const float* W    = z ? Wk_ : Wq_;
    const float* bias = z ? bk_ : bq_;
    float*       C    = z ? Ck  : Cq;
    const float outScale = z ? 1.0f : SCALE;

    __shared__ float As[16][136];
    __shared__ float Ws[16][132];

    const int t  = threadIdx.x;
    const int tx = t & 15;
    const int ty = t >> 4;
    const int m0 = blockIdx.y * 128;
    const int n0 = blockIdx.x * 128;

    float acc[8][8];
#pragma unroll
    for (int i = 0; i < 8; ++i)
#pragma unroll
        for (int j = 0; j < 8; ++j) acc[i][j] = 0.f;

    for (int kb = 0; kb < K; kb += 16) {
        __syncthreads();
#pragma unroll
        for (int it = 0; it < 2; ++it) {
            int f4  = t + it * 256;
            int row = f4 >> 2;
            int cg  = (f4 & 3) * 4;
            float4 av = *(const float4*)&A[(size_t)(m0 + row) * K + kb + cg];
            As[cg + 0][row] = av.x;
            As[cg + 1][row] = av.y;
            As[cg + 2][row] = av.z;
            As[cg + 3][row] = av.w;
        }
#pragma unroll
        for (int it = 0; it < 2; ++it) {
            int f4 = t + it * 256;
            int kk = f4 >> 5;
            int cb = (f4 & 31) * 4;
            *(float4*)&Ws[kk][cb] = *(const float4*)&W[(size_t)(kb + kk) * N + n0 + cb];
        }
        __syncthreads();
#pragma unroll
        for (int kk = 0; kk < 16; ++kk) {
            float4 a0 = *(const float4*)&As[kk][ty * 8];
            float4 a1 = *(const float4*)&As[kk][ty * 8 + 4];
            float4 w0 = *(const float4*)&Ws[kk][tx * 8];
            float4 w1 = *(const float4*)&Ws[kk][tx * 8 + 4];
            float a[8] = {a0.x, a0.y, a0.z, a0.w, a1.x, a1.y, a1.z, a1.w};
            float w[8] = {w0.x, w0.y, w0.z, w0.w, w1.x, w1.y, w1.z, w1.w};
#pragma unroll
            for (int i = 0; i < 8; ++i)
#pragma unroll
                for (int j = 0; j < 8; ++j)
                    acc[i][j] = fmaf(a[i], w[j], acc[i][j]);
        }
    }

    float4 b0 = *(const float4*)&bias[n0 + tx * 8];
    float4 b1 = *(const float4*)&bias[n0 + tx * 8 + 4];
#pragma unroll
    for (int i = 0; i < 8; ++i) {
        float4 o0 = make_float4((acc[i][0] + b0.x) * outScale, (acc[i][1] + b0.y) * outScale,
                                (acc[i][2] + b0.z) * outScale, (acc[i][3] + b0.w) * outScale);
        float4 o1 = make_float4((acc[i][4] + b1.x) * outScale, (acc[i][5] + b1.y) * outScale,
                                (acc[i][6] + b1.z) * outScale, (acc[i][7] + b1.w) * outScale);
        size_t off = (size_t)(m0 + ty * 8 + i) * N + n0 + tx * 8;
        *(float4*)&C[off]     = o0;
        *(float4*)&C[off + 4] = o1;
    }
}

// ---------------------------------------------------------------------------
// Dual transpose + split: grid.z selects Wv or Wo. fp32 W[K][N] -> bf16 hi/lo
// T[N][K]. Pure data movement + identical rounding -> bit-identical.
// ---------------------------------------------------------------------------
__global__ __launch_bounds__(256)
void transpose_split_dual(const float* __restrict__ Wv_, unsigned short* __restrict__ VhT,
                          unsigned short* __restrict__ VlT,
                          const float* __restrict__ Wo_, unsigned short* __restrict__ OhT,
                          unsigned short* __restrict__ OlT, int N, int K)
{
    const int z = blockIdx.z;
    const float* W = z ? Wo_ : Wv_;
    unsigned short* Th = z ? OhT : VhT;
    unsigned short* Tl = z ? OlT : VlT;

    __shared__ float tile[32][33];
    const int n0 = blockIdx.x * 32;
    const int k0 = blockIdx.y * 32;
    const int tx = threadIdx.x & 31;
    const int ty = threadIdx.x >> 5;   // 0..7

#pragma unroll
    for (int i = ty; i < 32; i += 8)
        tile[i][tx] = W[(size_t)(k0 + i) * N + n0 + tx];
    __syncthreads();
#pragma unroll
    for (int i = ty; i < 32; i += 8) {
        float x = tile[tx][i];                     // = W[k0+tx][n0+i]
        unsigned short h = bf16_rne(x);
        float hf = __uint_as_float((unsigned int)h << 16);
        unsigned short l = bf16_rne(x - hf);
        Th[(size_t)(n0 + i) * K + k0 + tx] = h;
        Tl[(size_t)(n0 + i) * K + k0 + tx] = l;
    }
}

// ---------------------------------------------------------------------------
// Split-bf16 MFMA GEMM (R11-proven): C = A(fp32) @ W + bias, W pre-transposed
// bf16 hi/lo. 3 passes: hi*hi + hi*lo + lo*hi.
// ---------------------------------------------------------------------------
__global__ __launch_bounds__(256, 1)
void gemm_mfma_split(const float* __restrict__ A, const unsigned short* __restrict__ Bh,
                     const unsigned short* __restrict__ Bl, const float* __restrict__ bias,
                     float* __restrict__ C, int M, int N, int K)
{
    constexpr int LDT = 56;
    __shared__ unsigned short Ah[128 * LDT];
    __shared__ unsigned short Al[128 * LDT];
    __shared__ unsigned short Wh[128 * LDT];
    __shared__ unsigned short Wl[128 * LDT];

    const int t    = threadIdx.x;
    const int lane = t & 63;
    const int w    = t >> 6;
    const int wr   = w >> 1;
    const int wc   = w & 1;
    const int l15  = lane & 15;
    const int l4   = lane >> 4;
    const int m0   = blockIdx.y * 128;
    const int n0   = blockIdx.x * 128;

    f32x4 acc[4][4];
#pragma unroll
    for (int m = 0; m < 4; ++m)
#pragma unroll
        for (int n = 0; n < 4; ++n) {
            f32x4 z = {0.f, 0.f, 0.f, 0.f};
            acc[m][n] = z;
        }

#pragma unroll 1
    for (int kb = 0; kb < K; kb += 32) {
        __syncthreads();
#pragma unroll
        for (int it = 0; it < 4; ++it) {
            int f   = t + it * 256;
            int row = f >> 3;
            int kg  = (f & 7) * 4;
            float4 av = *(const float4*)&A[(size_t)(m0 + row) * K + kb + kg];
            ushort4 hv, lv;
            hv.x = bf16_rne(av.x); lv.x = bf16_rne(av.x - __uint_as_float((unsigned int)hv.x << 16));
            hv.y = bf16_rne(av.y); lv.y = bf16_rne(av.y - __uint_as_float((unsigned int)hv.y << 16));
            hv.z = bf16_rne(av.z); lv.z = bf16_rne(av.z - __uint_as_float((unsigned int)hv.z << 16));
            hv.w = bf16_rne(av.w); lv.w = bf16_rne(av.w - __uint_as_float((unsigned int)hv.w << 16));
            *(ushort4*)&Ah[row * LDT + kg] = hv;
            *(ushort4*)&Al[row * LDT + kg] = lv;
            ushort4 bh4 = *(const ushort4*)&Bh[(size_t)(n0 + row) * K + kb + kg];
            ushort4 bl4 = *(const ushort4*)&Bl[(size_t)(n0 + row) * K + kb + kg];
            *(ushort4*)&Wh[row * LDT + kg] = bh4;
            *(ushort4*)&Wl[row * LDT + kg] = bl4;
        }
        __syncthreads();

        short8 ah[4], al[4], bh[4], bl[4];
#pragma unroll
        for (int m = 0; m < 4; ++m) {
            int row = wr * 64 + m * 16 + l15;
            ah[m] = *(short8*)&Ah[row * LDT + l4 * 8];
            al[m] = *(short8*)&Al[row * LDT + l4 * 8];
        }
#pragma unroll
        for (int n = 0; n < 4; ++n) {
            int col = wc * 64 + n * 16 + l15;
            bh[n] = *(short8*)&Wh[col * LDT + l4 * 8];
            bl[n] = *(short8*)&Wl[col * LDT + l4 * 8];
        }
#pragma unroll
        for (int m = 0; m < 4; ++m)
#pragma unroll
            for (int n = 0; n < 4; ++n)
                acc[m][n] = __builtin_amdgcn_mfma_f32_16x16x32_bf16(ah[m], bh[n], acc[m][n], 0, 0, 0);
#pragma unroll
        for (int m = 0; m < 4; ++m)
#pragma unroll
            for (int n = 0; n < 4; ++n)
                acc[m][n] = __builtin_amdgcn_mfma_f32_16x16x32_bf16(ah[m], bl[n], acc[m][n], 0, 0, 0);
#pragma unroll
        for (int m = 0; m < 4; ++m)
#pragma unroll
            for (int n = 0; n < 4; ++n)
                acc[m][n] = __builtin_amdgcn_mfma_f32_16x16x32_bf16(al[m], bh[n], acc[m][n], 0, 0, 0);
    }

#pragma unroll
    for (int m = 0; m < 4; ++m) {
        int row = m0 + wr * 64 + m * 16 + l4 * 4;
#pragma unroll
        for (int n = 0; n < 4; ++n) {
            int col = n0 + wc * 64 + n * 16 + l15;
            float bv = bias[col];
#pragma unroll
            for (int r = 0; r < 4; ++r)
                C[(size_t)(row + r) * N + col] = acc[m][n][r] + bv;
        }
    }
}

// ---------------------------------------------------------------------------
// Fused score + top-k select + PV gather. Score/selection identical to the
// R9-proven 387us kernel (bit-identical). Compaction now goes to the dead
// sclds row (weights at [pos], idx-bits at [512+pos]); the gather replicates
// pv_gather's exact summation order -> bit-identical output. Needs Vp ready.
// ---------------------------------------------------------------------------
__global__ __launch_bounds__(512, 1)
void score_select_gather(const float* __restrict__ Qp, const float* __restrict__ Kp,
                         const float* __restrict__ Vp, float* __restrict__ Oh)
{
    __shared__ float  sclds[8][2048];   // 64 KB
    __shared__ float4 Qlds4[8][8];      // 1 KB (pre-scaled Q)

    const int t    = threadIdx.x;
    const int lane = t & 63;
    const int wv   = t >> 6;            // 0..7

    const int wgid = blockIdx.x;
    const int xcd  = wgid & 7;
    const int jj   = wgid >> 3;              // 0..1023
    const int bh   = xcd + 8 * (jj >> 8);    // 0..31
    const int tile = jj & 255;
    const int b    = bh >> 4;
    const int h    = bh & 15;
    const int lbase = tile * 8;

    const float* kbase = Kp + (size_t)b * S * (H * R) + h * R;
    const float* qbase = Qp + (size_t)(b * L + lbase) * (H * R) + h * R;

    if (t < 64) {
        int row = t >> 3, q = t & 7;
        Qlds4[row][q] = *(const float4*)(qbase + (size_t)row * (H * R) + q * 4);
    }
    __syncthreads();

#pragma unroll 1
    for (int c = 0; c < 4; ++c) {
        float4 ka[8];
        const float* kp = kbase + (size_t)(c * 512 + wv * 64 + lane) * (H * R);
#pragma unroll
        for (int q = 0; q < 8; ++q) ka[q] = *(const float4*)(kp + q * 4);

        int zero;
        asm volatile("v_mov_b32 %0, 0" : "=v"(zero));

        const int keyl = c * 512 + wv * 64 + lane;
#pragma unroll
        for (int r = 0; r < 8; ++r) {
            const float4* qrow = Qlds4[r + zero];
            float s = 0.f;
#pragma unroll
            for (int q = 0; q < 8; ++q) {
                float4 qv = qrow[q];
                s = fmaf(qv.x, ka[q].x, s);
                s = fmaf(qv.y, ka[q].y, s);
                s = fmaf(qv.z, ka[q].z, s);
                s = fmaf(qv.w, ka[q].w, s);
            }
            sclds[r][keyl] = s;
        }
    }

    __syncthreads();

    const unsigned long long lanelt = (1ull << lane) - 1ull;
    {
        const int r = wv;

        float sreg[32];
#pragma unroll
        for (int j = 0; j < 32; ++j) sreg[j] = sclds[r][j * 64 + lane];

        float mx = sreg[0];
#pragma unroll
        for (int j = 1; j < 32; ++j) mx = fmaxf(mx, sreg[j]);
#pragma unroll
        for (int off = 32; off >= 1; off >>= 1)
            mx = fmaxf(mx, __shfl_xor(mx, off, 64));

#pragma unroll
        for (int j = 0; j < 32; ++j) {
            unsigned int bb  = __float_as_uint(sreg[j]);
            unsigned int sgn = (unsigned int)(((int)bb) >> 31);
            sreg[j] = __uint_as_float(bb ^ (sgn | 0x80000000u));
        }

        unsigned int P = 0;
        for (int bit = 31; bit >= 0; --bit) {
            unsigned int test = P | (1u << bit);
            int c2 = 0;
#pragma unroll
            for (int j = 0; j < 32; ++j)
                c2 += (int)__popcll(__ballot(__float_as_uint(sreg[j]) >= test));
            if (c2 >= TOPK) {
                P = test;
                if (c2 == TOPK) break;
            }
        }

        // exp pass: compact (weight, idx-bits) into the dead sclds row
        float dsum = 0.f;
        int   base = 0;
#pragma unroll
        for (int j = 0; j < 32; ++j) {
            unsigned int u = __float_as_uint(sreg[j]);
            bool sel = (u >= P);
            unsigned int sg2  = (unsigned int)(((int)u) >> 31);
            unsigned int mask = 0x80000000u | ~sg2;
            float forig = __uint_as_float(u ^ mask);
            float e = __expf(forig - mx);
            unsigned long long m = __ballot(sel);
            if (sel) {
                int pos = base + (int)__popcll(m & lanelt);
                if (pos < SELCAP) {
                    sclds[r][pos]       = e;
                    sclds[r][512 + pos] = __uint_as_float((unsigned int)(j * 64 + lane));
                }
            }
            dsum += sel ? e : 0.f;
            base += (int)__popcll(m);
        }
#pragma unroll
        for (int off = 32; off >= 1; off >>= 1)
            dsum += __shfl_xor(dsum, off, 64);

        // ---- fused PV gather (exact pv_gather summation order) ----
        const int cn = base < SELCAP ? base : SELCAP;
        const float inv = 1.0f / dsum;
        const float* vb = Vp + (size_t)b * S * DM + h * DH + lane;

        float a0 = 0.f, a1 = 0.f, a2 = 0.f, a3 = 0.f;
        int tt = 0;
        for (; tt + 4 <= cn; tt += 4) {
            int   s0 = (int)__float_as_uint(sclds[r][512 + tt + 0]);
            int   s1 = (int)__float_as_uint(sclds[r][512 + tt + 1]);
            int   s2 = (int)__float_as_uint(sclds[r][512 + tt + 2]);
            int   s3 = (int)__float_as_uint(sclds[r][512 + tt + 3]);
            float w0 = sclds[r][tt + 0], w1 = sclds[r][tt + 1];
            float w2 = sclds[r][tt + 2], w3 = sclds[r][tt + 3];
            a0 = fmaf(w0, vb[(size_t)s0 * DM], a0);
            a1 = fmaf(w1, vb[(size_t)s1 * DM], a1);
            a2 = fmaf(w2, vb[(size_t)s2 * DM], a2);
            a3 = fmaf(w3, vb[(size_t)s3 * DM], a3);
        }
        for (; tt < cn; ++tt) {
            int s0 = (int)__float_as_uint(sclds[r][512 + tt]);
            a0 = fmaf(sclds[r][tt], vb[(size_t)s0 * DM], a0);
        }
        Oh[(size_t)(b * L + lbase + r) * DM + h * DH + lane] = ((a0 + a1) + (a2 + a3)) * inv;
    }
}

// ---------------------------------------------------------------------------
extern "C" void kernel_launch(void* const* d_in, const int* in_sizes, int n_in,
                              void* d_out, int out_size, void* d_ws, size_t ws_size,
                              hipStream_t stream)
{
    const float* q  = (const float*)d_in[0];
    const float* k  = (const float*)d_in[1];
    const float* v  = (const float*)d_in[2];
    const float* Wq = (const float*)d_in[3];
    const float* bq = (const float*)d_in[4];
    const float* Wk = (const float*)d_in[5];
    const float* bk = (const float*)d_in[6];
    const float* Wv = (const float*)d_in[7];
    const float* bv = (const float*)d_in[8];
    const float* Wo = (const float*)d_in[9];
    const float* bo = (const float*)d_in[10];
    // d_in[11] = pos_bias: per-head additive constant -> top-k/softmax invariant -> no-op.

    float* out = (float*)d_out;
    char*  ws  = (char*)d_ws;

    const size_t MB = 1024 * 1024;
    float* Qp = (float*)(ws);             //  8 MiB (pre-scaled Q)
    float* Kp = (float*)(ws + 8  * MB);   //  8 MiB
    float* Vp = (float*)(ws + 16 * MB);   // 16 MiB
    float* Oh = (float*)(ws + 32 * MB);   // 16 MiB
    unsigned short* WvH = (unsigned short*)(ws + 48 * MB);  // 2 MiB each
    unsigned short* WvL = (unsigned short*)(ws + 50 * MB);
    unsigned short* WoH = (unsigned short*)(ws + 52 * MB);
    unsigned short* WoL = (unsigned short*)(ws + 54 * MB);

    const int M = B * L;  // 4096
    dim3 blk(256);

    // 1. both weight transposes (independent of everything)
    transpose_split_dual<<<dim3(DM / 32, DM / 32, 2), blk, 0, stream>>>(
        Wv, WvH, WvL, Wo, WoH, WoL, DM, DM);

    // 2. V projection (split-bf16 MFMA) — before the fused attention
    gemm_mfma_split<<<dim3(DM / 128, M / 128), blk, 0, stream>>>(v, WvH, WvL, bv, Vp, M, DM, DM);

    // 3. Q and K projections merged (fp32, bit-identical; fills 256 CUs)
    qk_proj<<<dim3((H * R) / 128, M / 128, 2), blk, 0, stream>>>(
        q, Wq, bq, Qp, k, Wk, bk, Kp, M, H * R, DM);

    // 4. fused scores + exact top-k + softmax + PV gather
    score_select_gather<<<dim3(8192), dim3(512), 0, stream>>>(Qp, Kp, Vp, Oh);

    // 5. output projection (split-bf16 MFMA)
    gemm_mfma_split<<<dim3(DM / 128, M / 128), blk, 0, stream>>>(Oh, WoH, WoL, bo, out, M, DM, DM);
}